// Round 9
// baseline (635.634 us; speedup 1.0000x reference)
//
#include <hip/hip_runtime.h>
#include <math.h>

typedef unsigned int uint;
typedef unsigned short ushort;

// ---------- helpers ----------
__device__ __forceinline__ float b2f(ushort u){
  union { uint i; float f; } v; v.i = ((uint)u) << 16; return v.f;
}
__device__ __forceinline__ ushort f2b(float f){
  union { float f; uint i; } v; v.f = f;
  uint i = v.i;
  i += 0x7fffu + ((i >> 16) & 1u);   // RNE
  return (ushort)(i >> 16);
}
__device__ __forceinline__ float wred(float v){
  #pragma unroll
  for (int s = 32; s > 0; s >>= 1) v += __shfl_xor(v, s, 64);
  return v;
}
// reduction within 16-lane groups (4-deep chain)
__device__ __forceinline__ float gred16(float v){
  v += __shfl_xor(v, 1, 64);
  v += __shfl_xor(v, 2, 64);
  v += __shfl_xor(v, 4, 64);
  v += __shfl_xor(v, 8, 64);
  return v;
}
__device__ __forceinline__ float sane(float v){ return isfinite(v) ? v : 0.f; }
__device__ __forceinline__ int iclamp(int v, int lo, int hi){ return v < lo ? lo : (v > hi ? hi : v); }
__device__ __forceinline__ void cp8(float d[8], const float s[8]){
  #pragma unroll
  for (int e = 0; e < 8; ++e) d[e] = s[e];
}

// raw 8-element chunk load for lane-position p (no normalization)
__device__ __forceinline__ void load_raw8(const void* emb, int isf, int it, int p, float x[8]){
  if (it >= 0){
    if (isf){
      const float4* q = (const float4*)((const float*)emb + (size_t)it * 128);
      float4 u = q[p * 2], u2 = q[p * 2 + 1];
      x[0] = u.x; x[1] = u.y; x[2] = u.z; x[3] = u.w;
      x[4] = u2.x; x[5] = u2.y; x[6] = u2.z; x[7] = u2.w;
    } else {
      uint4 u = ((const uint4*)((const ushort*)emb + (size_t)it * 128))[p];
      x[0] = b2f((ushort)u.x); x[1] = b2f((ushort)(u.x >> 16));
      x[2] = b2f((ushort)u.y); x[3] = b2f((ushort)(u.y >> 16));
      x[4] = b2f((ushort)u.z); x[5] = b2f((ushort)(u.z >> 16));
      x[6] = b2f((ushort)u.w); x[7] = b2f((ushort)(u.w >> 16));
    }
  } else {
    #pragma unroll
    for (int e = 0; e < 8; ++e) x[e] = 0.f;
  }
}

// per-block inline dtype detect: reads first 1 KB of emb (L2-hot after first
// block). f32 data read as bf16 pairs -> huge/NaN with pr ~0.45 per half;
// 512 halves checked => misdetect pr ~1e-67.
__device__ __forceinline__ int detect_isf(const void* emb, int t, int* s_flag){
  if (t == 0) *s_flag = 0;
  __syncthreads();
  if (t < 64){
    uint4 u = ((const uint4*)emb)[t];
    uint w[4] = { u.x, u.y, u.z, u.w };
    int bad = 0;
    #pragma unroll
    for (int e = 0; e < 4; ++e){
      float v0 = fabsf(b2f((ushort)w[e]));
      float v1 = fabsf(b2f((ushort)(w[e] >> 16)));
      if (!(v0 <= 1e4f) || !(v1 <= 1e4f)) bad = 1;
    }
    if (bad) *s_flag = 1;
  }
  __syncthreads();
  return *s_flag;
}

// B=1024, L=200, H=128, HEADS=8, D=16, N_NODE=200000, MAXN=201
#define OUTB 131072

// canonical f32 weight layout (float offsets inside wts)
#define C_W0T 0        // 128x128, W0T[k*128+h] = W0[h,k]
#define C_W1  16384    // 128x128 as-is
#define C_W2T 32768    // transposed
#define C_WQT 49152    // transposed
#define C_WTT 65536    // 256x128, WtT[k*128+h] = Wt[h,k]
#define C_B0  98304
#define C_B1  98432
#define C_B2  98560
#define C_BQ  98688
#define C_BT  98816
#define C_G   98944
#define C_BB  99072
#define C_TOT 99200

// dynamic LDS (bytes): two 22784-B batch slots (main blocks carry 2 batches):
//  per slot: [0,16384) s_w1p 64x128 bf16 (reused as s_part 4096 f32),
//            [16384,22784) s_alpha 1600 f32
//  bout blocks use [0,16512) as a 32 x 129 f32 tile.
#define SLOT_SZ 22784
#define KFUSED_SMEM (2 * SLOT_SZ)

#define NB_MAINB 512   // 512 blocks x 2 batches = 1024
#define NB_BOUT  3125  // 64 cols each
#define NB_TOT   (NB_MAINB + NB_BOUT)

// ---------- weight conversion (tiny, runs first) ----------
__global__ __launch_bounds__(256) void k_wts(
    const void* __restrict__ emb,
    const void* W0, const void* b0, const void* W1, const void* b1,
    const void* W2, const void* b2, const void* Wq, const void* bq,
    const void* Wt, const void* bt, const void* g, const void* bb,
    float* __restrict__ wts){
  __shared__ int s_flag;
  const int t = threadIdx.x;
  const int isf = detect_isf(emb, t, &s_flag);
  int j = blockIdx.x * 256 + t;
  if (j >= C_TOT) return;
  const void* src; int si;
  if (j < 16384)      { int k = j >> 7, h = j & 127; src = W0; si = h * 128 + k; }
  else if (j < 32768) { src = W1; si = j - 16384; }
  else if (j < 49152) { int i = j - 32768; int k = i >> 7, h = i & 127; src = W2; si = h * 128 + k; }
  else if (j < 65536) { int i = j - 49152; int k = i >> 7, h = i & 127; src = Wq; si = h * 128 + k; }
  else if (j < 98304) { int i = j - 65536; int k = i >> 7, h = i & 127; src = Wt; si = h * 256 + k; }
  else {
    int i = j - 98304; int arr = i >> 7;
    const void* tab[7] = { b0, b1, b2, bq, bt, g, bb };
    src = tab[arr]; si = i & 127;
  }
  wts[j] = isf ? ((const float*)src)[si] : b2f(((const ushort*)src)[si]);
}

// ---------- bout path (512 threads): 64 cols, two 32-row passes.
// Nontemporal writes keep the 95 MB output out of L2/L3 so emb stays
// resident for the concurrent main blocks.
__device__ void bout_block(const void* __restrict__ emb, int isf,
                           void* __restrict__ outv, int bb, int t, char* dsm){
  float* tile = (float*)dsm;                 // 32 x 129 f32
  const int gid = t >> 4, p = t & 15;        // gid 0..31
  const int base = bb * 64;
  for (int pass = 0; pass < 2; ++pass){
    const int pb = base + pass * 32;
    if (pass) __syncthreads();               // pass-0 writes done before reuse
    {
      int gi = pb + gid;                     // 32 groups cover 32 rows
      if (gi < 199999){
        float x[8];
        load_raw8(emb, isf, gi + 1, p, x);
        float ss = 0.f;
        #pragma unroll
        for (int e = 0; e < 8; ++e) ss += x[e] * x[e];
        ss = gred16(ss);
        float inv = 1.f / (sqrtf(ss) + 1e-12f);
        #pragma unroll
        for (int e = 0; e < 8; ++e) tile[gid * 129 + p * 8 + e] = x[e] * inv;
      }
    }
    __syncthreads();
    // write 128 h x 32 n (32 threads per h-row)
    #pragma unroll
    for (int it = 0; it < 8; ++it){
      int idx = it * 512 + t;
      int h = idx >> 5, n = idx & 31;
      int gi = pb + n;
      if (gi < 199999){
        float val = sane(tile[n * 129 + h]);
        if (isf){
          float* op = (float*)outv + OUTB + (size_t)h * 199999 + gi;
          __builtin_nontemporal_store(val, op);
        } else {
          ushort* op = (ushort*)outv + OUTB + (size_t)h * 199999 + gi;
          __builtin_nontemporal_store(f2b(val), op);
        }
      }
    }
  }
}

// ---------- fused: 512 main blocks (2 batches each) + 3125 bout blocks ----------
__global__ __launch_bounds__(512) void k_fused(
    const int* __restrict__ alias_, const int* __restrict__ items,
    const int* __restrict__ mask, const void* __restrict__ emb,
    const float* __restrict__ wts, void* __restrict__ outv){
  extern __shared__ __align__(16) char dsm[];
  __shared__ int s_flag;
  __shared__ float s_X0[2][128], s_ht[2][128], s_a[2][128], s_hts[2][128];
  __shared__ float s_c1[2][64];
  __shared__ float s_T[2][8], s_Tp[2][64];
  __shared__ float s_red[2][16];
  __shared__ float s_nrm[2][200];  // per-row inverse norm (phase b -> phase d)
  __shared__ int   s_it[2][200];   // resolved item index per row (-1 = masked)
  __shared__ int   s_item[2];

  const int t = threadIdx.x;
  const int isf = detect_isf(emb, t, &s_flag);

  // Bresenham spread of 512 main blocks over the grid
  const int bid = blockIdx.x;
  const int m = (bid * NB_MAINB) / NB_TOT;
  const bool is_main = ((bid + 1) * NB_MAINB) / NB_TOT > m;
  if (!is_main){
    bout_block(emb, isf, outv, bid - m, t, dsm);
    return;
  }

  const int half = t >> 8;       // 0 or 1: which batch this half-block owns
  const int tb = t & 255;
  const int b = m * 2 + half;

  char* mydsm = dsm + half * SLOT_SZ;
  ushort* s_w1p   = (ushort*)mydsm;                   // 64*128 bf16
  float*  s_part  = (float*)mydsm;                    // reuse after phase b
  float*  s_alpha = (float*)(mydsm + 16384);          // 1600 f32

  const int wv = tb >> 6, gid = tb >> 4, p = tb & 15, lane = tb & 63;
  const int mbase = b * 200;

  // ---- prep: len, s_it ----
  int mv = 0;
  if (tb < 200){
    mv = mask[mbase + tb];
    int a = mv ? iclamp(alias_[mbase + tb], 0, 200) : 0;
    s_it[half][tb] = mv ? iclamp(items[b * 201 + a], 0, 199999) : -1;
  }
  float lv = wred((float)mv);
  if ((tb & 63) == 0) s_red[half][tb >> 6] = lv;
  __syncthreads();

  // hoisted phase-b prefetch: first two gathers issued now; latency covered
  // by the prep matvecs below.
  float xc[8], xn1[8];
  load_raw8(emb, isf, s_it[half][gid], p, xc);
  load_raw8(emb, isf, s_it[half][gid + 16], p, xn1);

  const int len = iclamp((int)(s_red[half][0] + s_red[half][1] +
                               s_red[half][2] + s_red[half][3] + 0.5f), 1, 200);
  if (tb == 0){
    int a = iclamp(alias_[mbase + len - 1], 0, 200);
    s_item[half] = iclamp(items[b * 201 + a], 0, 199999);
  }
  __syncthreads();

  // ht_last: gather + double normalize (threads 0..127 of each half)
  float v = 0.f;
  if (tb < 128)
    v = isf ? ((const float*)emb)[(size_t)s_item[half] * 128 + tb]
            : b2f(((const ushort*)emb)[(size_t)s_item[half] * 128 + tb]);
  float ss = wred(v * v);
  if ((tb & 63) == 0) s_red[half][4 + (tb >> 6)] = ss;
  __syncthreads();
  v = v / (sqrtf(s_red[half][4] + s_red[half][5]) + 1e-12f);
  float ss2 = wred(v * v);
  if ((tb & 63) == 0) s_red[half][8 + (tb >> 6)] = ss2;
  __syncthreads();
  v = v / (sqrtf(s_red[half][8] + s_red[half][9]) + 1e-12f);
  if (tb < 128) s_ht[half][tb] = v;
  __syncthreads();

  // hts = x/(|x|+eps): sign-like, f64 accumulate; 4 accumulators break the
  // 128-deep dependent-FMA chain.
  if (tb < 128){
    double d0 = 0.0, d1 = 0.0, d2 = 0.0, d3 = 0.0;
    for (int k = 0; k < 128; k += 4){
      d0 += (double)wts[C_WQT + (k    ) * 128 + tb] * (double)s_ht[half][k    ];
      d1 += (double)wts[C_WQT + (k + 1) * 128 + tb] * (double)s_ht[half][k + 1];
      d2 += (double)wts[C_WQT + (k + 2) * 128 + tb] * (double)s_ht[half][k + 2];
      d3 += (double)wts[C_WQT + (k + 3) * 128 + tb] * (double)s_ht[half][k + 3];
    }
    float a = (float)((double)wts[C_BQ + tb] + ((d0 + d1) + (d2 + d3)));
    s_hts[half][tb] = a / (fabsf(a) + 1e-12f);
  }
  __syncthreads();
  if (tb < 128){
    float a0 = 0.f, a1 = 0.f, a2 = 0.f, a3 = 0.f;
    for (int k = 0; k < 128; k += 4){
      a0 += wts[C_W0T + (k    ) * 128 + tb] * s_hts[half][k    ];
      a1 += wts[C_W0T + (k + 1) * 128 + tb] * s_hts[half][k + 1];
      a2 += wts[C_W0T + (k + 2) * 128 + tb] * s_hts[half][k + 2];
      a3 += wts[C_W0T + (k + 3) * 128 + tb] * s_hts[half][k + 3];
    }
    s_X0[half][tb] = wts[C_B0 + tb] + ((a0 + a1) + (a2 + a3));
  }
  __syncthreads();
  if (tb < 64){
    int head = tb >> 3, j = tb & 7;
    float c = 0.f;
    #pragma unroll
    for (int d = 0; d < 16; ++d) c += s_X0[half][head * 16 + d] * wts[C_B1 + j * 16 + d];
    s_c1[half][tb] = c;
  }

  // ---- W1p[head*8+j][k] = sum_d X0[head*16+d] * W1[j*16+d, k], bf16 in LDS ----
  __syncthreads();
  for (int idx = tb; idx < 8192; idx += 256){
    int hj = idx >> 7, k = idx & 127, head = hj >> 3, j = hj & 7;
    float acc = 0.f;
    const float* w1r = wts + C_W1 + (j * 16) * 128 + k;
    #pragma unroll
    for (int d = 0; d < 16; ++d) acc += s_X0[half][head * 16 + d] * w1r[d * 128];
    s_w1p[hj * 128 + k] = f2b(acc);
  }
  __syncthreads();

  // phase b: per row (16-lane group) -- gather (depth-2 prefetch), single
  // normalize, cache inverse norm, 8 logits per row.
  {
    float xt[8];
    for (int r = gid; r < 200; r += 16){
      int rn = r + 32;
      load_raw8(emb, isf, rn < 200 ? s_it[half][rn] : -1, p, xt);

      int head = r / 25, lb = (r % 25) * 8;
      uint4 wu[8];
      #pragma unroll
      for (int j = 0; j < 8; ++j)
        wu[j] = *(const uint4*)(s_w1p + (head * 8 + j) * 128 + p * 8);

      float ssr = 0.f;
      #pragma unroll
      for (int e = 0; e < 8; ++e) ssr += xc[e] * xc[e];
      ssr = gred16(ssr);
      float inv = 1.f / (sqrtf(ssr) + 1e-12f);   // masked row: xc==0 -> stays 0
      #pragma unroll
      for (int e = 0; e < 8; ++e) xc[e] *= inv;
      if (p == 0) s_nrm[half][r] = inv;

      #pragma unroll
      for (int j = 0; j < 8; ++j){
        float dot = xc[0] * b2f((ushort)wu[j].x) + xc[1] * b2f((ushort)(wu[j].x >> 16))
                  + xc[2] * b2f((ushort)wu[j].y) + xc[3] * b2f((ushort)(wu[j].y >> 16))
                  + xc[4] * b2f((ushort)wu[j].z) + xc[5] * b2f((ushort)(wu[j].z >> 16))
                  + xc[6] * b2f((ushort)wu[j].w) + xc[7] * b2f((ushort)(wu[j].w >> 16));
        dot = gred16(dot);
        if (p == 0){
          float logit = s_c1[half][head * 8 + j] + dot;
          s_alpha[(lb + j) * 8 + head] = 2.f / (1.f + expf(-logit));
        }
      }
      cp8(xc, xn1); cp8(xn1, xt);
    }
  }
  __syncthreads();

  // phase c: softmax over all 200 positions per head
  {
    int head = tb >> 5, l32 = tb & 31;
    float vals[7]; float mx = -1e30f;
    #pragma unroll
    for (int i = 0; i < 7; ++i){
      int l = l32 + 32 * i;
      float xx = (l < 200) ? s_alpha[l * 8 + head] : -1e30f;
      vals[i] = xx; mx = fmaxf(mx, xx);
    }
    #pragma unroll
    for (int s = 16; s > 0; s >>= 1) mx = fmaxf(mx, __shfl_xor(mx, s, 64));
    float sum = 0.f; float e[7];
    #pragma unroll
    for (int i = 0; i < 7; ++i){
      int l = l32 + 32 * i;
      float ex = (l < 200) ? expf(vals[i] - mx) : 0.f;
      e[i] = ex; sum += ex;
    }
    #pragma unroll
    for (int s = 16; s > 0; s >>= 1) sum += __shfl_xor(sum, s, 64);
    float inv = 1.f / sum;
    #pragma unroll
    for (int i = 0; i < 7; ++i){
      int l = l32 + 32 * i;
      if (l < 200) s_alpha[l * 8 + head] = e[i] * inv;
    }
  }
  __syncthreads();

  // T[h] = sum_{l<len} alpha[l,h]
  if (tb < 64){
    int h = tb & 7, seg = tb >> 3;
    int l0 = seg * 25, l1 = l0 + 25; if (l1 > len) l1 = len;
    float s = 0.f;
    for (int l = l0; l < l1; ++l) s += s_alpha[l * 8 + h];
    s_Tp[half][tb] = s;
  }
  __syncthreads();
  if (tb < 8){
    float s = 0.f;
    #pragma unroll
    for (int seg = 0; seg < 8; ++seg) s += s_Tp[half][seg * 8 + tb];
    s_T[half][tb] = s;
  }

  // phase d: re-gather all rows (L2/L3-warm, depth-2 prefetch), scale by the
  // cached inverse norm, accumulate alpha-weighted head sums.
  float acc[64];
  #pragma unroll
  for (int e = 0; e < 64; ++e) acc[e] = 0.f;
  {
    float ha[8], hb[8], ht8[8];
    load_raw8(emb, isf, s_it[half][gid], p, ha);
    load_raw8(emb, isf, gid + 16 < 200 ? s_it[half][gid + 16] : -1, p, hb);
    for (int l = gid; l < 200; l += 16){
      int lc = l + 32;
      load_raw8(emb, isf, lc < 200 ? s_it[half][lc] : -1, p, ht8);
      if (s_it[half][l] >= 0){
        float nm = s_nrm[half][l];
        float x[8];
        #pragma unroll
        for (int e = 0; e < 8; ++e) x[e] = ha[e] * nm;
        float4 a0 = *(const float4*)(s_alpha + l * 8);
        float4 a1 = *(const float4*)(s_alpha + l * 8 + 4);
        float al[8] = { a0.x, a0.y, a0.z, a0.w, a1.x, a1.y, a1.z, a1.w };
        #pragma unroll
        for (int h = 0; h < 8; ++h)
          #pragma unroll
          for (int e = 0; e < 8; ++e) acc[h * 8 + e] += al[h] * x[e];
      }
      cp8(ha, hb); cp8(hb, ht8);
    }
  }
  // reduce across the 4 groups within each wave
  #pragma unroll
  for (int e = 0; e < 64; ++e){
    float vv = acc[e];
    vv += __shfl_xor(vv, 16, 64);
    vv += __shfl_xor(vv, 32, 64);
    acc[e] = vv;
  }
  __syncthreads();   // W1p dead from here, region reused as s_part
  if (lane < 16){
    #pragma unroll
    for (int h = 0; h < 8; ++h)
      #pragma unroll
      for (int e = 0; e < 8; ++e)
        s_part[wv * 1024 + h * 128 + p * 8 + e] = acc[h * 8 + e];
  }
  __syncthreads();
  for (int i = tb; i < 1024; i += 256)
    s_part[i] = s_part[i] + s_part[1024 + i] + s_part[2048 + i] + s_part[3072 + i];
  __syncthreads();

  // phase e: a_raw = s_hl . W2T + T*b2 ; layernorm
  float araw = 0.f;
  if (tb < 128){
    int head = tb >> 4;
    const float* hl = &s_part[head * 128];
    float a0 = 0.f, a1 = 0.f, a2 = 0.f, a3 = 0.f;
    for (int k = 0; k < 128; k += 4){
      a0 += hl[k    ] * wts[C_W2T + (k    ) * 128 + tb];
      a1 += hl[k + 1] * wts[C_W2T + (k + 1) * 128 + tb];
      a2 += hl[k + 2] * wts[C_W2T + (k + 2) * 128 + tb];
      a3 += hl[k + 3] * wts[C_W2T + (k + 3) * 128 + tb];
    }
    araw = wts[C_B2 + tb] * s_T[half][head] + ((a0 + a1) + (a2 + a3));
  }
  float v1 = wred(tb < 128 ? araw : 0.f);
  if ((tb & 63) == 0) s_red[half][tb >> 6] = v1;
  __syncthreads();
  float mu = (s_red[half][0] + s_red[half][1]) * 0.0078125f;
  float dd = (tb < 128) ? (araw - mu) : 0.f;
  float v2 = wred(dd * dd);
  if ((tb & 63) == 0) s_red[half][4 + (tb >> 6)] = v2;
  __syncthreads();
  float var = (s_red[half][4] + s_red[half][5]) * 0.0078125f;
  if (tb < 128)
    s_a[half][tb] = dd / sqrtf(var + 1e-8f) * wts[C_G + tb] + wts[C_BB + tb];
  __syncthreads();

  // phase f: out = normalize([a_ln | ht] . WtT + bt)
  float o = 0.f;
  if (tb < 128){
    float o0 = 0.f, o1 = 0.f, o2 = 0.f, o3 = 0.f;
    for (int k = 0; k < 128; k += 2){
      o0 += s_a[half][k    ] * wts[C_WTT + (k      ) * 128 + tb];
      o1 += s_a[half][k + 1] * wts[C_WTT + (k + 1  ) * 128 + tb];
      o2 += s_ht[half][k   ] * wts[C_WTT + (128 + k) * 128 + tb];
      o3 += s_ht[half][k+ 1] * wts[C_WTT + (129 + k) * 128 + tb];
    }
    o = wts[C_BT + tb] + ((o0 + o1) + (o2 + o3));
  }
  float v3 = wred(tb < 128 ? o * o : 0.f);
  if ((tb & 63) == 0) s_red[half][8 + (tb >> 6)] = v3;
  __syncthreads();
  float nrm = sqrtf(s_red[half][8] + s_red[half][9]);
  if (tb < 128){
    float val = sane(o / (nrm + 1e-12f));
    if (isf) ((float*)outv)[b * 128 + tb] = val;
    else     ((ushort*)outv)[b * 128 + tb] = f2b(val);
  }
}

extern "C" void kernel_launch(void* const* d_in, const int* in_sizes, int n_in,
                              void* d_out, int out_size, void* d_ws, size_t ws_size,
                              hipStream_t stream){
  const int* alias_ = (const int*)d_in[0];
  const int* items  = (const int*)d_in[1];
  const int* mask   = (const int*)d_in[2];
  const void* emb = d_in[3];
  const void* W0  = d_in[4];
  const void* b0  = d_in[5];
  const void* W1  = d_in[6];
  const void* b1  = d_in[7];
  const void* W2  = d_in[8];
  const void* b2_ = d_in[9];
  const void* Wq  = d_in[10];
  const void* bq  = d_in[11];
  const void* Wt  = d_in[12];
  const void* bt  = d_in[13];
  const void* g_  = d_in[14];
  const void* bb_ = d_in[15];

  char* ws = (char*)d_ws;
  float* wts = (float*)ws;                    // 396,800 B

  static int g_attr_done = 0;
  if (!g_attr_done){
    hipError_t e = hipFuncSetAttribute(reinterpret_cast<const void*>(k_fused),
                        hipFuncAttributeMaxDynamicSharedMemorySize, KFUSED_SMEM);
    (void)e;
    g_attr_done = 1;
  }

  k_wts  <<<dim3(388),    dim3(256), 0,           stream>>>(emb, W0, b0, W1, b1,
                                                  W2, b2_, Wq, bq, Wt, bt, g_, bb_, wts);
  k_fused<<<dim3(NB_TOT), dim3(512), KFUSED_SMEM, stream>>>(alias_, items, mask, emb,
                                                  wts, d_out);
}

// Round 10
// 353.917 us; speedup vs baseline: 1.7960x; 1.7960x over previous
//
#include <hip/hip_runtime.h>
#include <math.h>

typedef unsigned int uint;
typedef unsigned short ushort;
typedef float vf2 __attribute__((ext_vector_type(2)));

// ---------- helpers ----------
__device__ __forceinline__ float b2f(ushort u){
  union { uint i; float f; } v; v.i = ((uint)u) << 16; return v.f;
}
__device__ __forceinline__ ushort f2b(float f){
  union { float f; uint i; } v; v.f = f;
  uint i = v.i;
  i += 0x7fffu + ((i >> 16) & 1u);   // RNE
  return (ushort)(i >> 16);
}
__device__ __forceinline__ float wred(float v){
  #pragma unroll
  for (int s = 32; s > 0; s >>= 1) v += __shfl_xor(v, s, 64);
  return v;
}
// reduction within 16-lane groups (4-deep chain)
__device__ __forceinline__ float gred16(float v){
  v += __shfl_xor(v, 1, 64);
  v += __shfl_xor(v, 2, 64);
  v += __shfl_xor(v, 4, 64);
  v += __shfl_xor(v, 8, 64);
  return v;
}
__device__ __forceinline__ float sane(float v){ return isfinite(v) ? v : 0.f; }
__device__ __forceinline__ int iclamp(int v, int lo, int hi){ return v < lo ? lo : (v > hi ? hi : v); }
__device__ __forceinline__ void cp8(float d[8], const float s[8]){
  #pragma unroll
  for (int e = 0; e < 8; ++e) d[e] = s[e];
}

// raw 8-element chunk load for lane-position p (no normalization)
__device__ __forceinline__ void load_raw8(const void* emb, int isf, int it, int p, float x[8]){
  if (it >= 0){
    if (isf){
      const float4* q = (const float4*)((const float*)emb + (size_t)it * 128);
      float4 u = q[p * 2], u2 = q[p * 2 + 1];
      x[0] = u.x; x[1] = u.y; x[2] = u.z; x[3] = u.w;
      x[4] = u2.x; x[5] = u2.y; x[6] = u2.z; x[7] = u2.w;
    } else {
      uint4 u = ((const uint4*)((const ushort*)emb + (size_t)it * 128))[p];
      x[0] = b2f((ushort)u.x); x[1] = b2f((ushort)(u.x >> 16));
      x[2] = b2f((ushort)u.y); x[3] = b2f((ushort)(u.y >> 16));
      x[4] = b2f((ushort)u.z); x[5] = b2f((ushort)(u.z >> 16));
      x[6] = b2f((ushort)u.w); x[7] = b2f((ushort)(u.w >> 16));
    }
  } else {
    #pragma unroll
    for (int e = 0; e < 8; ++e) x[e] = 0.f;
  }
}

// per-block inline dtype detect: reads first 1 KB of emb (L2-hot after first
// block). f32 data read as bf16 pairs -> huge/NaN with pr ~0.45 per half;
// 512 halves checked => misdetect pr ~1e-67.
__device__ __forceinline__ int detect_isf(const void* emb, int t, int* s_flag){
  if (t == 0) *s_flag = 0;
  __syncthreads();
  if (t < 64){
    uint4 u = ((const uint4*)emb)[t];
    uint w[4] = { u.x, u.y, u.z, u.w };
    int bad = 0;
    #pragma unroll
    for (int e = 0; e < 4; ++e){
      float v0 = fabsf(b2f((ushort)w[e]));
      float v1 = fabsf(b2f((ushort)(w[e] >> 16)));
      if (!(v0 <= 1e4f) || !(v1 <= 1e4f)) bad = 1;
    }
    if (bad) *s_flag = 1;
  }
  __syncthreads();
  return *s_flag;
}

// B=1024, L=200, H=128, HEADS=8, D=16, N_NODE=200000, MAXN=201
#define OUTB 131072

// canonical f32 weight layout (float offsets inside wts)
#define C_W0T 0        // 128x128, W0T[k*128+h] = W0[h,k]
#define C_W1  16384    // 128x128 as-is
#define C_W2T 32768    // transposed
#define C_WQT 49152    // transposed
#define C_WTT 65536    // 256x128, WtT[k*128+h] = Wt[h,k]
#define C_B0  98304
#define C_B1  98432
#define C_B2  98560
#define C_BQ  98688
#define C_BT  98816
#define C_G   98944
#define C_BB  99072
#define C_TOT 99200

// dynamic LDS layout (bytes), shared by both fused paths:
//  main blocks: [0,16384) s_w1p 64x128 bf16 (reused as s_part 4096 f32),
//               [16384,22784) s_alpha 1600 f32
//  bout blocks: [0,16512) tile 32 x 129 f32
// Total with ~4.6 KB static -> ~27.4 KB -> 5 blocks/CU for every block.
#define KFUSED_SMEM 22784

#define NB_MAIN 1024
#define NB_BOUT 3125   // 64 cols each
#define NB_TOT  4149

// ---------- weight conversion (tiny, runs first) ----------
__global__ __launch_bounds__(256) void k_wts(
    const void* __restrict__ emb,
    const void* W0, const void* b0, const void* W1, const void* b1,
    const void* W2, const void* b2, const void* Wq, const void* bq,
    const void* Wt, const void* bt, const void* g, const void* bb,
    float* __restrict__ wts){
  __shared__ int s_flag;
  const int t = threadIdx.x;
  const int isf = detect_isf(emb, t, &s_flag);
  int j = blockIdx.x * 256 + t;
  if (j >= C_TOT) return;
  const void* src; int si;
  if (j < 16384)      { int k = j >> 7, h = j & 127; src = W0; si = h * 128 + k; }
  else if (j < 32768) { src = W1; si = j - 16384; }
  else if (j < 49152) { int i = j - 32768; int k = i >> 7, h = i & 127; src = W2; si = h * 128 + k; }
  else if (j < 65536) { int i = j - 49152; int k = i >> 7, h = i & 127; src = Wq; si = h * 128 + k; }
  else if (j < 98304) { int i = j - 65536; int k = i >> 7, h = i & 127; src = Wt; si = h * 256 + k; }
  else {
    int i = j - 98304; int arr = i >> 7;
    const void* tab[7] = { b0, b1, b2, bq, bt, g, bb };
    src = tab[arr]; si = i & 127;
  }
  wts[j] = isf ? ((const float*)src)[si] : b2f(((const ushort*)src)[si]);
}

// ---------- bout path: 64 cols, two 32-row passes through a 16.5 KB tile.
// Parity-aware vectorized nontemporal writes: even h-rows are 8B/4B-aligned
// (199999 odd), odd rows fall back to scalars. Nontemporal keeps the 95 MB
// output out of L2/L3 so emb stays resident for the concurrent main blocks.
__device__ void bout_block(const void* __restrict__ emb, int isf,
                           void* __restrict__ outv, int bb, int t, char* dsm){
  float* tile = (float*)dsm;                 // 32 x 129 f32
  const int gid = t >> 4, p = t & 15;
  const int base = bb * 64;
  for (int pass = 0; pass < 2; ++pass){
    const int pb = base + pass * 32;
    if (pass) __syncthreads();               // pass-0 writes done before reuse
    for (int i = gid; i < 32; i += 16){
      int gi = pb + i;
      if (gi < 199999){
        float x[8];
        load_raw8(emb, isf, gi + 1, p, x);
        float ss = 0.f;
        #pragma unroll
        for (int e = 0; e < 8; ++e) ss += x[e] * x[e];
        ss = gred16(ss);
        float inv = 1.f / (sqrtf(ss) + 1e-12f);
        #pragma unroll
        for (int e = 0; e < 8; ++e) tile[i * 129 + p * 8 + e] = x[e] * inv;
      }
    }
    __syncthreads();
    // write 128 h x 16 row-pairs: idx -> h = idx>>4, n2 = (idx&15)*2.
    // 16 threads per h-row write 2 elems each -> 128 B contiguous segments.
    #pragma unroll
    for (int it = 0; it < 8; ++it){
      int idx = it * 256 + t;
      int h = idx >> 4, n2 = (idx & 15) * 2;
      int gi = pb + n2;
      if (isf){
        float* op = (float*)outv + OUTB + (size_t)h * 199999 + gi;
        float w0 = sane(tile[n2 * 129 + h]);
        float w1 = sane(tile[(n2 + 1) * 129 + h]);
        if (!(h & 1) && gi + 1 < 199999){
          vf2 w2; w2.x = w0; w2.y = w1;
          __builtin_nontemporal_store(w2, (vf2*)op);
        } else {
          if (gi < 199999)     __builtin_nontemporal_store(w0, op);
          if (gi + 1 < 199999) __builtin_nontemporal_store(w1, op + 1);
        }
      } else {
        ushort* op = (ushort*)outv + OUTB + (size_t)h * 199999 + gi;
        ushort w0 = f2b(sane(tile[n2 * 129 + h]));
        ushort w1 = f2b(sane(tile[(n2 + 1) * 129 + h]));
        if (!(h & 1) && gi + 1 < 199999){
          uint w = (uint)w0 | ((uint)w1 << 16);
          __builtin_nontemporal_store(w, (uint*)op);
        } else {
          if (gi < 199999)     __builtin_nontemporal_store(w0, op);
          if (gi + 1 < 199999) __builtin_nontemporal_store(w1, op + 1);
        }
      }
    }
  }
}

// ---------- fused: blocks [0,1024) = main (start first, run long);
// blocks [1024,4149) = bout (stream behind them) ----------
__global__ __launch_bounds__(256) void k_fused(
    const int* __restrict__ alias_, const int* __restrict__ items,
    const int* __restrict__ mask, const void* __restrict__ emb,
    const float* __restrict__ wts, void* __restrict__ outv){
  extern __shared__ __align__(16) char dsm[];
  __shared__ int s_flag;
  __shared__ float s_X0[128], s_ht[128], s_a[128], s_hts[128];
  __shared__ float s_c1[64];
  __shared__ float s_T[8], s_Tp[64];
  __shared__ float s_red[16];
  __shared__ float s_nrm[200];    // per-row inverse norm (phase b -> phase d)
  __shared__ int   s_it[200];     // resolved item index per row (-1 = masked)
  __shared__ int   s_item;

  const int t = threadIdx.x;
  const int isf = detect_isf(emb, t, &s_flag);

  const int bid = blockIdx.x;
  if (bid >= NB_MAIN){
    bout_block(emb, isf, outv, bid - NB_MAIN, t, dsm);
    return;
  }
  const int b = bid;

  ushort* s_w1p   = (ushort*)dsm;                     // 64*128 bf16
  float*  s_part  = (float*)dsm;                      // reuse after phase b
  float*  s_alpha = (float*)(dsm + 16384);            // 1600 f32

  const int wv = t >> 6, gid = t >> 4, p = t & 15, lane = t & 63;
  const int mbase = b * 200;

  // ---- prep: len, s_it ----
  int mv = 0;
  if (t < 200){
    mv = mask[mbase + t];
    int a = mv ? iclamp(alias_[mbase + t], 0, 200) : 0;
    s_it[t] = mv ? iclamp(items[b * 201 + a], 0, 199999) : -1;
  }
  float lv = wred((float)mv);
  if ((t & 63) == 0) s_red[t >> 6] = lv;
  __syncthreads();

  // hoisted phase-b prefetch: first two gathers issued now; latency covered
  // by the prep matvecs below.
  float xc[8], xn1[8];
  load_raw8(emb, isf, s_it[gid], p, xc);
  load_raw8(emb, isf, s_it[gid + 16], p, xn1);

  const int len = iclamp((int)(s_red[0] + s_red[1] + s_red[2] + s_red[3] + 0.5f), 1, 200);
  if (t == 0){
    int a = iclamp(alias_[mbase + len - 1], 0, 200);
    s_item = iclamp(items[b * 201 + a], 0, 199999);
  }
  __syncthreads();

  // ht_last: gather + double normalize (threads 0..127)
  float v = 0.f;
  if (t < 128)
    v = isf ? ((const float*)emb)[(size_t)s_item * 128 + t]
            : b2f(((const ushort*)emb)[(size_t)s_item * 128 + t]);
  float ss = wred(v * v);
  if ((t & 63) == 0) s_red[4 + (t >> 6)] = ss;
  __syncthreads();
  v = v / (sqrtf(s_red[4] + s_red[5]) + 1e-12f);
  float ss2 = wred(v * v);
  if ((t & 63) == 0) s_red[8 + (t >> 6)] = ss2;
  __syncthreads();
  v = v / (sqrtf(s_red[8] + s_red[9]) + 1e-12f);
  if (t < 128) s_ht[t] = v;
  __syncthreads();

  // hts = x/(|x|+eps): sign-like, f64 accumulate; 4 accumulators break the
  // 128-deep dependent-FMA chain.
  if (t < 128){
    double d0 = 0.0, d1 = 0.0, d2 = 0.0, d3 = 0.0;
    for (int k = 0; k < 128; k += 4){
      d0 += (double)wts[C_WQT + (k    ) * 128 + t] * (double)s_ht[k    ];
      d1 += (double)wts[C_WQT + (k + 1) * 128 + t] * (double)s_ht[k + 1];
      d2 += (double)wts[C_WQT + (k + 2) * 128 + t] * (double)s_ht[k + 2];
      d3 += (double)wts[C_WQT + (k + 3) * 128 + t] * (double)s_ht[k + 3];
    }
    float a = (float)((double)wts[C_BQ + t] + ((d0 + d1) + (d2 + d3)));
    s_hts[t] = a / (fabsf(a) + 1e-12f);
  }
  __syncthreads();
  if (t < 128){
    float a0 = 0.f, a1 = 0.f, a2 = 0.f, a3 = 0.f;
    for (int k = 0; k < 128; k += 4){
      a0 += wts[C_W0T + (k    ) * 128 + t] * s_hts[k    ];
      a1 += wts[C_W0T + (k + 1) * 128 + t] * s_hts[k + 1];
      a2 += wts[C_W0T + (k + 2) * 128 + t] * s_hts[k + 2];
      a3 += wts[C_W0T + (k + 3) * 128 + t] * s_hts[k + 3];
    }
    s_X0[t] = wts[C_B0 + t] + ((a0 + a1) + (a2 + a3));
  }
  __syncthreads();
  if (t < 64){
    int head = t >> 3, j = t & 7;
    float c = 0.f;
    #pragma unroll
    for (int d = 0; d < 16; ++d) c += s_X0[head * 16 + d] * wts[C_B1 + j * 16 + d];
    s_c1[t] = c;
  }

  // ---- W1p[head*8+j][k] = sum_d X0[head*16+d] * W1[j*16+d, k], bf16 in LDS ----
  __syncthreads();
  for (int idx = t; idx < 8192; idx += 256){
    int hj = idx >> 7, k = idx & 127, head = hj >> 3, j = hj & 7;
    float acc = 0.f;
    const float* w1r = wts + C_W1 + (j * 16) * 128 + k;
    #pragma unroll
    for (int d = 0; d < 16; ++d) acc += s_X0[head * 16 + d] * w1r[d * 128];
    s_w1p[hj * 128 + k] = f2b(acc);
  }
  __syncthreads();

  // phase b: per row (16-lane group) -- gather (depth-2 prefetch), single
  // normalize, cache inverse norm, 8 logits per row.
  {
    float xt[8];
    for (int r = gid; r < 200; r += 16){
      int rn = r + 32;
      load_raw8(emb, isf, rn < 200 ? s_it[rn] : -1, p, xt);

      int head = r / 25, lb = (r % 25) * 8;
      uint4 wu[8];
      #pragma unroll
      for (int j = 0; j < 8; ++j)
        wu[j] = *(const uint4*)(s_w1p + (head * 8 + j) * 128 + p * 8);

      float ssr = 0.f;
      #pragma unroll
      for (int e = 0; e < 8; ++e) ssr += xc[e] * xc[e];
      ssr = gred16(ssr);
      float inv = 1.f / (sqrtf(ssr) + 1e-12f);   // masked row: xc==0 -> stays 0
      #pragma unroll
      for (int e = 0; e < 8; ++e) xc[e] *= inv;
      if (p == 0) s_nrm[r] = inv;

      #pragma unroll
      for (int j = 0; j < 8; ++j){
        float dot = xc[0] * b2f((ushort)wu[j].x) + xc[1] * b2f((ushort)(wu[j].x >> 16))
                  + xc[2] * b2f((ushort)wu[j].y) + xc[3] * b2f((ushort)(wu[j].y >> 16))
                  + xc[4] * b2f((ushort)wu[j].z) + xc[5] * b2f((ushort)(wu[j].z >> 16))
                  + xc[6] * b2f((ushort)wu[j].w) + xc[7] * b2f((ushort)(wu[j].w >> 16));
        dot = gred16(dot);
        if (p == 0){
          float logit = s_c1[head * 8 + j] + dot;
          s_alpha[(lb + j) * 8 + head] = 2.f / (1.f + expf(-logit));
        }
      }
      cp8(xc, xn1); cp8(xn1, xt);
    }
  }
  __syncthreads();

  // phase c: softmax over all 200 positions per head
  {
    int head = t >> 5, l32 = t & 31;
    float vals[7]; float mx = -1e30f;
    #pragma unroll
    for (int i = 0; i < 7; ++i){
      int l = l32 + 32 * i;
      float xx = (l < 200) ? s_alpha[l * 8 + head] : -1e30f;
      vals[i] = xx; mx = fmaxf(mx, xx);
    }
    #pragma unroll
    for (int s = 16; s > 0; s >>= 1) mx = fmaxf(mx, __shfl_xor(mx, s, 64));
    float sum = 0.f; float e[7];
    #pragma unroll
    for (int i = 0; i < 7; ++i){
      int l = l32 + 32 * i;
      float ex = (l < 200) ? expf(vals[i] - mx) : 0.f;
      e[i] = ex; sum += ex;
    }
    #pragma unroll
    for (int s = 16; s > 0; s >>= 1) sum += __shfl_xor(sum, s, 64);
    float inv = 1.f / sum;
    #pragma unroll
    for (int i = 0; i < 7; ++i){
      int l = l32 + 32 * i;
      if (l < 200) s_alpha[l * 8 + head] = e[i] * inv;
    }
  }
  __syncthreads();

  // T[h] = sum_{l<len} alpha[l,h]
  if (t < 64){
    int h = t & 7, seg = t >> 3;
    int l0 = seg * 25, l1 = l0 + 25; if (l1 > len) l1 = len;
    float s = 0.f;
    for (int l = l0; l < l1; ++l) s += s_alpha[l * 8 + h];
    s_Tp[t] = s;
  }
  __syncthreads();
  if (t < 8){
    float s = 0.f;
    #pragma unroll
    for (int seg = 0; seg < 8; ++seg) s += s_Tp[seg * 8 + t];
    s_T[t] = s;
  }

  // phase d: re-gather all rows (L2/L3-warm, depth-2 prefetch), scale by the
  // cached inverse norm, accumulate alpha-weighted head sums.
  float acc[64];
  #pragma unroll
  for (int e = 0; e < 64; ++e) acc[e] = 0.f;
  {
    float ha[8], hb[8], ht8[8];
    load_raw8(emb, isf, s_it[gid], p, ha);
    load_raw8(emb, isf, gid + 16 < 200 ? s_it[gid + 16] : -1, p, hb);
    for (int l = gid; l < 200; l += 16){
      int lc = l + 32;
      load_raw8(emb, isf, lc < 200 ? s_it[lc] : -1, p, ht8);
      if (s_it[l] >= 0){
        float nm = s_nrm[l];
        float x[8];
        #pragma unroll
        for (int e = 0; e < 8; ++e) x[e] = ha[e] * nm;
        float4 a0 = *(const float4*)(s_alpha + l * 8);
        float4 a1 = *(const float4*)(s_alpha + l * 8 + 4);
        float al[8] = { a0.x, a0.y, a0.z, a0.w, a1.x, a1.y, a1.z, a1.w };
        #pragma unroll
        for (int h = 0; h < 8; ++h)
          #pragma unroll
          for (int e = 0; e < 8; ++e) acc[h * 8 + e] += al[h] * x[e];
      }
      cp8(ha, hb); cp8(hb, ht8);
    }
  }
  // reduce across the 4 groups within each wave
  #pragma unroll
  for (int e = 0; e < 64; ++e){
    float vv = acc[e];
    vv += __shfl_xor(vv, 16, 64);
    vv += __shfl_xor(vv, 32, 64);
    acc[e] = vv;
  }
  __syncthreads();   // W1p dead from here, region reused as s_part
  if (lane < 16){
    #pragma unroll
    for (int h = 0; h < 8; ++h)
      #pragma unroll
      for (int e = 0; e < 8; ++e)
        s_part[wv * 1024 + h * 128 + p * 8 + e] = acc[h * 8 + e];
  }
  __syncthreads();
  for (int i = t; i < 1024; i += 256)
    s_part[i] = s_part[i] + s_part[1024 + i] + s_part[2048 + i] + s_part[3072 + i];
  __syncthreads();

  // phase e: a_raw = s_hl . W2T + T*b2 ; layernorm
  float araw = 0.f;
  if (t < 128){
    int head = t >> 4;
    const float* hl = &s_part[head * 128];
    float a0 = 0.f, a1 = 0.f, a2 = 0.f, a3 = 0.f;
    for (int k = 0; k < 128; k += 4){
      a0 += hl[k    ] * wts[C_W2T + (k    ) * 128 + t];
      a1 += hl[k + 1] * wts[C_W2T + (k + 1) * 128 + t];
      a2 += hl[k + 2] * wts[C_W2T + (k + 2) * 128 + t];
      a3 += hl[k + 3] * wts[C_W2T + (k + 3) * 128 + t];
    }
    araw = wts[C_B2 + t] * s_T[head] + ((a0 + a1) + (a2 + a3));
  }
  float v1 = wred(t < 128 ? araw : 0.f);
  if ((t & 63) == 0) s_red[t >> 6] = v1;
  __syncthreads();
  float mu = (s_red[0] + s_red[1]) * 0.0078125f;
  float dd = (t < 128) ? (araw - mu) : 0.f;
  float v2 = wred(dd * dd);
  if ((t & 63) == 0) s_red[4 + (t >> 6)] = v2;
  __syncthreads();
  float var = (s_red[4] + s_red[5]) * 0.0078125f;
  if (t < 128)
    s_a[t] = dd / sqrtf(var + 1e-8f) * wts[C_G + t] + wts[C_BB + t];
  __syncthreads();

  // phase f: out = normalize([a_ln | ht] . WtT + bt)
  float o = 0.f;
  if (t < 128){
    float o0 = 0.f, o1 = 0.f, o2 = 0.f, o3 = 0.f;
    for (int k = 0; k < 128; k += 2){
      o0 += s_a[k    ] * wts[C_WTT + (k      ) * 128 + t];
      o1 += s_a[k + 1] * wts[C_WTT + (k + 1  ) * 128 + t];
      o2 += s_ht[k   ] * wts[C_WTT + (128 + k) * 128 + t];
      o3 += s_ht[k+ 1] * wts[C_WTT + (129 + k) * 128 + t];
    }
    o = wts[C_BT + t] + ((o0 + o1) + (o2 + o3));
  }
  float v3 = wred(t < 128 ? o * o : 0.f);
  if ((t & 63) == 0) s_red[8 + (t >> 6)] = v3;
  __syncthreads();
  float nrm = sqrtf(s_red[8] + s_red[9]);
  if (t < 128){
    float val = sane(o / (nrm + 1e-12f));
    if (isf) ((float*)outv)[b * 128 + t] = val;
    else     ((ushort*)outv)[b * 128 + t] = f2b(val);
  }
}

extern "C" void kernel_launch(void* const* d_in, const int* in_sizes, int n_in,
                              void* d_out, int out_size, void* d_ws, size_t ws_size,
                              hipStream_t stream){
  const int* alias_ = (const int*)d_in[0];
  const int* items  = (const int*)d_in[1];
  const int* mask   = (const int*)d_in[2];
  const void* emb = d_in[3];
  const void* W0  = d_in[4];
  const void* b0  = d_in[5];
  const void* W1  = d_in[6];
  const void* b1  = d_in[7];
  const void* W2  = d_in[8];
  const void* b2_ = d_in[9];
  const void* Wq  = d_in[10];
  const void* bq  = d_in[11];
  const void* Wt  = d_in[12];
  const void* bt  = d_in[13];
  const void* g_  = d_in[14];
  const void* bb_ = d_in[15];

  char* ws = (char*)d_ws;
  float* wts = (float*)ws;                    // 396,800 B

  static int g_attr_done = 0;
  if (!g_attr_done){
    hipError_t e = hipFuncSetAttribute(reinterpret_cast<const void*>(k_fused),
                        hipFuncAttributeMaxDynamicSharedMemorySize, KFUSED_SMEM);
    (void)e;
    g_attr_done = 1;
  }

  k_wts  <<<dim3(388),    dim3(256), 0,           stream>>>(emb, W0, b0, W1, b1,
                                                  W2, b2_, Wq, bq, Wt, bt, g_, bb_, wts);
  k_fused<<<dim3(NB_TOT), dim3(256), KFUSED_SMEM, stream>>>(alias_, items, mask, emb,
                                                  wts, d_out);
}